// Round 7
// baseline (102.451 us; speedup 1.0000x reference)
//
#include <hip/hip_runtime.h>

// DeterministicEncoder: MLP encoder [M,2]->[M,64] + Laplace-kernel attention.
// exp(-|k-q|) factorizes: with context sorted by key, exclusive-prefix
// Lo[j] = sum_{i<j} e^{s_i} v_i and suffix Hi[j] = sum_{i>=j} e^{-s_i} v_i give
// out[n] = e^{-q} Lo[j_n] + e^{q} Hi[j_n], j_n = lower_bound(skey, q).
//
// Round 7: K1 emits PRE-SCALED, PRE-SORTED weight arrays wLo[c][r]=e^s v[c],
// wHi[c][r]=e^{-s} v[c] (it knows each row's rank at scatter time), so K2's
// front-end collapses from {stage sv+perm, 16 random ds_read gathers, 8 ks
// reads, 16 expf} to 4 coalesced float4 global loads. K2: 2 barriers, 101KB
// LDS. K1: W3 read as float2, e^{+/-s} computed once per row.

#define H    16
#define OUTD 64
#define MM   8192                 // context/target count, fixed by harness
#define PAD(i) ((i) + ((i) >> 5)) // LDS bank padding

// ---------------------------------------------------------------- K1
// 256 blocks x 1024. Block b: rank+scatter rows [32b,32b+32), MLP same rows,
// writes skey[r] and pre-scaled sorted weights wLo/wHi.
__global__ __launch_bounds__(1024) void rank_mlp_kernel(
    const float* __restrict__ xc, const float* __restrict__ yc,
    const float* __restrict__ W1, const float* __restrict__ b1,
    const float* __restrict__ W2, const float* __restrict__ b2,
    const float* __restrict__ W3, const float* __restrict__ b3,
    float* __restrict__ skey, float* __restrict__ wLo, float* __restrict__ wHi)
{
    __shared__ float sk[MM];          // all keys, 32 KB
    __shared__ int   red[32][4];      // [row][key-quarter] partial ranks
    __shared__ float sh2[32][H + 1];  // h2 per row, padded
    __shared__ int   sr[32];          // rank per row
    __shared__ float se[32], sei[32]; // e^{+s}, e^{-s} per row
    const int t = threadIdx.x;
    const int b = blockIdx.x;
    const int lane = t & 63, wid = t >> 6;

    for (int i = t; i < MM / 4; i += 1024)        // coalesced 16B staging
        ((float4*)sk)[i] = ((const float4*)xc)[i];
    __syncthreads();

    // rank: wave wid -> row-group rg = wid>>2 (8 rows), key-quarter qt = wid&3.
    // Lanes read CONTIGUOUS float4 (conflict-free); each lane compares its 4
    // keys against 8 broadcast row-keys; in-wave shfl reduction.
    {
        const int rg = wid >> 2, qt = wid & 3;
        const int m0 = b * 32 + rg * 8;
        float mk[8];
#pragma unroll
        for (int j = 0; j < 8; j++) mk[j] = sk[m0 + j];   // wave-uniform reads
        int cnt[8] = {0, 0, 0, 0, 0, 0, 0, 0};
#pragma unroll
        for (int ch = 0; ch < 8; ch++) {
            const int g = qt * 2048 + ch * 256 + lane * 4;
            const float4 k4 = *(const float4*)(sk + g);
#pragma unroll
            for (int j = 0; j < 8; j++) {
                const int m = m0 + j;
                const float k = mk[j];
                // strict total order on (key, index) -> rank is a permutation
                cnt[j] += (k4.x < k || (k4.x == k && (g + 0) < m)) ? 1 : 0;
                cnt[j] += (k4.y < k || (k4.y == k && (g + 1) < m)) ? 1 : 0;
                cnt[j] += (k4.z < k || (k4.z == k && (g + 2) < m)) ? 1 : 0;
                cnt[j] += (k4.w < k || (k4.w == k && (g + 3) < m)) ? 1 : 0;
            }
        }
#pragma unroll
        for (int j = 0; j < 8; j++) {
            int v = cnt[j];
#pragma unroll
            for (int off = 32; off; off >>= 1) v += __shfl_down(v, off);
            if (lane == 0) red[rg * 8 + j][qt] = v;
        }
    }

    // MLP stage 1 (t<32): h2 + e^{+/-s} once per row.
    if (t < 32) {
        const int m = b * 32 + t;
        const float x = sk[m], y = yc[m];
        se[t]  = __expf(x);
        sei[t] = __expf(-x);
        float h1[H];
#pragma unroll
        for (int j = 0; j < H; j++) {
            float a = x * W1[j] + y * W1[H + j] + b1[j];
            h1[j] = a > 0.f ? a : 0.f;
        }
#pragma unroll
        for (int j = 0; j < H; j++) {
            float a = b2[j];
#pragma unroll
            for (int i = 0; i < H; i++) a += h1[i] * W2[i * H + j];
            sh2[t][j] = a > 0.f ? a : 0.f;
        }
    }
    __syncthreads();

    // scatter (t<32): total rank, publish to LDS + write sorted key.
    if (t < 32) {
        const int m = b * 32 + t;
        const int r = red[t][0] + red[t][1] + red[t][2] + red[t][3];
        sr[t] = r;
        skey[r] = sk[m];
    }
    __syncthreads();

    // MLP stage 2: 32 threads/row x 2 channels; write pre-scaled sorted w.
    {
        const int ml = t >> 5, chp = t & 31;
        const int cb = chp * 2;
        const int r = sr[ml];
        const float es = se[ml], esi = sei[ml];
        float a0 = b3[cb], a1 = b3[cb + 1];
#pragma unroll
        for (int i = 0; i < H; i++) {
            const float h = sh2[ml][i];
            const float2 w2 = ((const float2*)(W3 + i * OUTD))[chp];
            a0 += h * w2.x;
            a1 += h * w2.y;
        }
        wLo[(size_t)cb * MM + r]       = es * a0;
        wLo[(size_t)(cb + 1) * MM + r] = es * a1;
        wHi[(size_t)cb * MM + r]       = esi * a0;
        wHi[(size_t)(cb + 1) * MM + r] = esi * a1;
    }
}

// ---------------------------------------------------------------- K2
// 256 blocks x 1024 = 64 channels x 4 target-quarters. Weights arrive
// pre-scaled+sorted: 4 coalesced float4 loads/thread, wave-shfl scans into
// LDS Lo/Hi tables, answer 2048 targets from LDS. 101KB LDS, 2 barriers.
__global__ __launch_bounds__(1024) void scan_query_kernel(
    const float* __restrict__ xt, const float* __restrict__ skey,
    const float* __restrict__ wLo, const float* __restrict__ wHi,
    float* __restrict__ out)
{
    __shared__ float sk [PAD(MM) + 1];
    __shared__ float sLo[PAD(MM) + 1];
    __shared__ float sHi[PAD(MM) + 1];
    __shared__ float wsA[16], wsB[16]; // per-wave scan totals (Lo / Hi)
    const int t = threadIdx.x;
    const int lane = t & 63, wid = t >> 6;
    const int c = blockIdx.x & 63;
    const int quarter = blockIdx.x >> 6;
    const int base = t * 8;

    for (int i = t; i < MM / 4; i += 1024) {      // coalesced key staging
        const float4 k4 = ((const float4*)skey)[i];
        sk[PAD(4 * i + 0)] = k4.x; sk[PAD(4 * i + 1)] = k4.y;
        sk[PAD(4 * i + 2)] = k4.z; sk[PAD(4 * i + 3)] = k4.w;
    }

    // coalesced pre-scaled weight loads (64 lanes x 32B contiguous)
    float wl[8], wh[8];
    {
        const float4* pL = (const float4*)(wLo + (size_t)c * MM) + 2 * t;
        const float4* pH = (const float4*)(wHi + (size_t)c * MM) + 2 * t;
        float4 a = pL[0], b4 = pL[1];
        wl[0] = a.x; wl[1] = a.y; wl[2] = a.z; wl[3] = a.w;
        wl[4] = b4.x; wl[5] = b4.y; wl[6] = b4.z; wl[7] = b4.w;
        a = pH[0]; b4 = pH[1];
        wh[0] = a.x; wh[1] = a.y; wh[2] = a.z; wh[3] = a.w;
        wh[4] = b4.x; wh[5] = b4.y; wh[6] = b4.z; wh[7] = b4.w;
    }

    // ---- wave scans (no LDS): Lo from left, Hi from right
    float S = 0.f, S2 = 0.f;
#pragma unroll
    for (int r = 0; r < 8; r++) { S += wl[r]; S2 += wh[r]; }
    float inc = S;
#pragma unroll
    for (int off = 1; off < 64; off <<= 1) {
        float a = __shfl_up(inc, (unsigned)off);
        if (lane >= off) inc += a;
    }
    float inc2 = S2;
#pragma unroll
    for (int off = 1; off < 64; off <<= 1) {
        float a = __shfl_down(inc2, (unsigned)off);
        if (lane + off < 64) inc2 += a;
    }
    if (lane == 63) wsA[wid] = inc;
    if (lane == 0)  wsB[wid] = inc2;
    __syncthreads();                   // covers sk staging + wsA/wsB

    float before = 0.f, after = 0.f;
#pragma unroll
    for (int ww = 0; ww < 16; ww++) {
        before += (ww < wid) ? wsA[ww] : 0.f;
        after  += (ww > wid) ? wsB[ww] : 0.f;
    }
    float run = before + inc - S;      // exclusive prefix offset of this chunk
#pragma unroll
    for (int r = 0; r < 8; r++) { sLo[PAD(base + r)] = run; run += wl[r]; }
    if (t == 1023) sLo[PAD(MM)] = run;
    float run2 = after + inc2 - S2;    // suffix sum strictly after this chunk
#pragma unroll
    for (int r = 7; r >= 0; r--) { run2 += wh[r]; sHi[PAD(base + r)] = run2; }
    if (t == 0) sHi[PAD(MM)] = 0.f;
    __syncthreads();

    // ---- query: two interleaved 13-step lower_bounds (2x ILP on the
    // dependent-LDS chains), then 2 LDS reads + 2 expf + store each.
    const int n0 = quarter * (MM / 4) + t;
    const int n1 = n0 + 1024;
    const float q0 = xt[n0], q1 = xt[n1];
    int lo0 = 0, hi0 = MM, lo1 = 0, hi1 = MM;
#pragma unroll
    for (int s = 0; s < 13; s++) {     // 8192 = 2^13: exactly 13 steps
        const int mid0 = (lo0 + hi0) >> 1;
        const int mid1 = (lo1 + hi1) >> 1;
        if (sk[PAD(mid0)] < q0) lo0 = mid0 + 1; else hi0 = mid0;
        if (sk[PAD(mid1)] < q1) lo1 = mid1 + 1; else hi1 = mid1;
    }
    out[(size_t)n0 * OUTD + c] = __expf(-q0) * sLo[PAD(lo0)]
                               + __expf(q0)  * sHi[PAD(lo0)];
    out[(size_t)n1 * OUTD + c] = __expf(-q1) * sLo[PAD(lo1)]
                               + __expf(q1)  * sHi[PAD(lo1)];
}

extern "C" void kernel_launch(void* const* d_in, const int* in_sizes, int n_in,
                              void* d_out, int out_size, void* d_ws, size_t ws_size,
                              hipStream_t stream)
{
    const float* xc = (const float*)d_in[0];
    const float* yc = (const float*)d_in[1];
    const float* xt = (const float*)d_in[2];
    const float* W1 = (const float*)d_in[3];
    const float* b1 = (const float*)d_in[4];
    const float* W2 = (const float*)d_in[5];
    const float* b2 = (const float*)d_in[6];
    const float* W3 = (const float*)d_in[7];
    const float* b3 = (const float*)d_in[8];
    float* out = (float*)d_out;

    // workspace: skey [MM] | wLo [64][MM] (2MB) | wHi [64][MM] (2MB)
    char* ws = (char*)d_ws;
    float* skey = (float*)ws;
    float* wLo  = (float*)(ws + (size_t)MM * 4);
    float* wHi  = wLo + (size_t)OUTD * MM;

    rank_mlp_kernel<<<256, 1024, 0, stream>>>(xc, yc, W1, b1, W2, b2, W3, b3,
                                              skey, wLo, wHi);
    scan_query_kernel<<<256, 1024, 0, stream>>>(xt, skey, wLo, wHi, out);
}

// Round 8
// 94.504 us; speedup vs baseline: 1.0841x; 1.0841x over previous
//
#include <hip/hip_runtime.h>

// DeterministicEncoder: MLP encoder [M,2]->[M,64] + Laplace-kernel attention.
// exp(-|k-q|) factorizes: with context sorted by key, exclusive-prefix
// Lo[j] = sum_{i<j} e^{s_i} v_i and suffix Hi[j] = sum_{i>=j} e^{-s_i} v_i give
// out[n] = e^{-q} Lo[j_n] + e^{q} Hi[j_n], j_n = lower_bound(skey, q).
//
// Round 8: revert round-7's pre-scaled-weights experiment (it doubled K1's
// scattered stores and K2's weight-stream bytes: 95.3 -> 102.5 us). Back to
// the round-6 structure, plus ONE fix: K1 stage-2 index swap (ml=t&31,
// chp=t>>5) so vT stores are coalesced (2x128B segments per instruction
// instead of 64 scattered dwords 64KB apart).

#define H    16
#define OUTD 64
#define MM   8192                 // context/target count, fixed by harness
#define PAD(i) ((i) + ((i) >> 5)) // LDS bank padding

// ---------------------------------------------------------------- K1
// 256 blocks x 1024. Block b: rank+scatter rows [32b,32b+32), MLP same rows.
__global__ __launch_bounds__(1024) void rank_mlp_kernel(
    const float* __restrict__ xc, const float* __restrict__ yc,
    const float* __restrict__ W1, const float* __restrict__ b1,
    const float* __restrict__ W2, const float* __restrict__ b2,
    const float* __restrict__ W3, const float* __restrict__ b3,
    float* __restrict__ vT, float* __restrict__ skey, int* __restrict__ perm)
{
    __shared__ float sk[MM];          // all keys, 32 KB
    __shared__ int   red[32][4];      // [row][key-quarter] partial ranks
    __shared__ float sh2[32][H + 1];  // h2 per row, padded (17: coprime to 32)
    const int t = threadIdx.x;
    const int b = blockIdx.x;
    const int lane = t & 63, wid = t >> 6;

    for (int i = t; i < MM / 4; i += 1024)        // coalesced 16B staging
        ((float4*)sk)[i] = ((const float4*)xc)[i];
    __syncthreads();

    // rank: wave wid -> row-group rg = wid>>2 (8 rows), key-quarter qt = wid&3.
    // Lanes read CONTIGUOUS float4 (conflict-free); each lane compares its 4
    // keys against 8 broadcast row-keys; in-wave shfl reduction.
    {
        const int rg = wid >> 2, qt = wid & 3;
        const int m0 = b * 32 + rg * 8;
        float mk[8];
#pragma unroll
        for (int j = 0; j < 8; j++) mk[j] = sk[m0 + j];   // wave-uniform reads
        int cnt[8] = {0, 0, 0, 0, 0, 0, 0, 0};
#pragma unroll
        for (int ch = 0; ch < 8; ch++) {
            const int g = qt * 2048 + ch * 256 + lane * 4;
            const float4 k4 = *(const float4*)(sk + g);
#pragma unroll
            for (int j = 0; j < 8; j++) {
                const int m = m0 + j;
                const float k = mk[j];
                // strict total order on (key, index) -> rank is a permutation
                cnt[j] += (k4.x < k || (k4.x == k && (g + 0) < m)) ? 1 : 0;
                cnt[j] += (k4.y < k || (k4.y == k && (g + 1) < m)) ? 1 : 0;
                cnt[j] += (k4.z < k || (k4.z == k && (g + 2) < m)) ? 1 : 0;
                cnt[j] += (k4.w < k || (k4.w == k && (g + 3) < m)) ? 1 : 0;
            }
        }
#pragma unroll
        for (int j = 0; j < 8; j++) {            // in-wave reduction
            int v = cnt[j];
#pragma unroll
            for (int off = 32; off; off >>= 1) v += __shfl_down(v, off);
            if (lane == 0) red[rg * 8 + j][qt] = v;
        }
    }

    // MLP stage 1: h2 once per row (t<32).
    if (t < 32) {
        const int m = b * 32 + t;
        const float x = sk[m], y = yc[m];
        float h1[H];
#pragma unroll
        for (int j = 0; j < H; j++) {
            float a = x * W1[j] + y * W1[H + j] + b1[j];
            h1[j] = a > 0.f ? a : 0.f;
        }
#pragma unroll
        for (int j = 0; j < H; j++) {
            float a = b2[j];
#pragma unroll
            for (int i = 0; i < H; i++) a += h1[i] * W2[i * H + j];
            sh2[t][j] = a > 0.f ? a : 0.f;
        }
    }
    __syncthreads();

    // scatter (t<32) -- 4-elem sum of partials, then direct sorted write.
    if (t < 32) {
        const int m = b * 32 + t;
        const int r = red[t][0] + red[t][1] + red[t][2] + red[t][3];
        skey[r] = sk[m];
        perm[r] = m;
    }

    // MLP stage 2: ml = t&31 (lane-fast ROW) so the vT stores from lanes 0-31
    // hit 32 consecutive floats of one channel -> coalesced 128B segments.
    // sh2 reads: stride 17 (coprime 32) -> conflict-free; W3/b3 half-wave
    // uniform -> broadcast.
    {
        const int ml = t & 31, chp = t >> 5;
        const int m = b * 32 + ml;
        const int cb = chp * 2;
        float a0 = b3[cb], a1 = b3[cb + 1];
#pragma unroll
        for (int i = 0; i < H; i++) {
            const float h = sh2[ml][i];
            const float2 w2 = ((const float2*)(W3 + i * OUTD))[chp];
            a0 += h * w2.x;
            a1 += h * w2.y;
        }
        vT[(size_t)cb * MM + m]       = a0;
        vT[(size_t)(cb + 1) * MM + m] = a1;
    }
}

// ---------------------------------------------------------------- K2
// 256 blocks x 1024 = 64 channels x 4 target-quarters. Stage skey + value row
// in LDS, wave-shfl Lo/Hi scans, answer 2048 targets from LDS. ~134KB LDS.
__global__ __launch_bounds__(1024) void scan_query_kernel(
    const float* __restrict__ xt, const float* __restrict__ skey,
    const int* __restrict__ perm, const float* __restrict__ vT,
    float* __restrict__ out)
{
    __shared__ float sk [PAD(MM) + 1];
    __shared__ float sLo[PAD(MM) + 1];
    __shared__ float sHi[PAD(MM) + 1];
    __shared__ float sv [MM];          // value row for this channel
    __shared__ float wsA[16], wsB[16]; // per-wave scan totals (Lo / Hi)
    const int t = threadIdx.x;
    const int lane = t & 63, wid = t >> 6;
    const int c = blockIdx.x & 63;
    const int quarter = blockIdx.x >> 6;
    const float* __restrict__ vrow = vT + (size_t)c * MM;

    for (int i = t; i < MM / 4; i += 1024) {    // coalesced 16B staging
        ((float4*)sv)[i] = ((const float4*)vrow)[i];
        const float4 k4 = ((const float4*)skey)[i];
        sk[PAD(4 * i + 0)] = k4.x; sk[PAD(4 * i + 1)] = k4.y;
        sk[PAD(4 * i + 2)] = k4.z; sk[PAD(4 * i + 3)] = k4.w;
    }
    __syncthreads();

    const int base = t * 8;
    float vv[8], ks[8];
    {
        const int4* pp = (const int4*)(perm + base);
        int4 p0 = pp[0], p1 = pp[1];
        vv[0] = sv[p0.x]; vv[1] = sv[p0.y]; vv[2] = sv[p0.z]; vv[3] = sv[p0.w];
        vv[4] = sv[p1.x]; vv[5] = sv[p1.y]; vv[6] = sv[p1.z]; vv[7] = sv[p1.w];
    }
#pragma unroll
    for (int r = 0; r < 8; r++) ks[r] = sk[PAD(base + r)];

    // ---- Lo: exclusive prefix of e^{s} v
    float w[8];
    float S = 0.f;
#pragma unroll
    for (int r = 0; r < 8; r++) { w[r] = __expf(ks[r]) * vv[r]; S += w[r]; }
    float inc = S;                         // wave inclusive scan (from left)
#pragma unroll
    for (int off = 1; off < 64; off <<= 1) {
        float a = __shfl_up(inc, (unsigned)off);
        if (lane >= off) inc += a;
    }
    if (lane == 63) wsA[wid] = inc;
    __syncthreads();
    float before = 0.f;
#pragma unroll
    for (int ww = 0; ww < 16; ww++) before += (ww < wid) ? wsA[ww] : 0.f;
    float run = before + inc - S;          // exclusive offset of this chunk
#pragma unroll
    for (int r = 0; r < 8; r++) { sLo[PAD(base + r)] = run; run += w[r]; }
    if (t == 1023) sLo[PAD(MM)] = run;

    // ---- Hi: suffix of e^{-s} v
    float S2 = 0.f;
#pragma unroll
    for (int r = 0; r < 8; r++) { w[r] = __expf(-ks[r]) * vv[r]; S2 += w[r]; }
    float inc2 = S2;                       // wave inclusive scan (from right)
#pragma unroll
    for (int off = 1; off < 64; off <<= 1) {
        float a = __shfl_down(inc2, (unsigned)off);
        if (lane + off < 64) inc2 += a;
    }
    if (lane == 0) wsB[wid] = inc2;
    __syncthreads();
    float after = 0.f;
#pragma unroll
    for (int ww = 0; ww < 16; ww++) after += (ww > wid) ? wsB[ww] : 0.f;
    float run2 = after + inc2 - S2;        // sum strictly after this chunk
#pragma unroll
    for (int r = 7; r >= 0; r--) { run2 += w[r]; sHi[PAD(base + r)] = run2; }
    if (t == 0) sHi[PAD(MM)] = 0.f;
    __syncthreads();

    // ---- query: two interleaved 13-step lower_bounds (independent dependent-
    // LDS chains -> 2x ILP), then 2 LDS reads + 2 expf + store each.
    const int n0 = quarter * (MM / 4) + t;
    const int n1 = n0 + 1024;
    const float q0 = xt[n0], q1 = xt[n1];
    int lo0 = 0, hi0 = MM, lo1 = 0, hi1 = MM;
#pragma unroll
    for (int s = 0; s < 13; s++) {         // 8192 = 2^13: exactly 13 steps
        const int mid0 = (lo0 + hi0) >> 1;
        const int mid1 = (lo1 + hi1) >> 1;
        if (sk[PAD(mid0)] < q0) lo0 = mid0 + 1; else hi0 = mid0;
        if (sk[PAD(mid1)] < q1) lo1 = mid1 + 1; else hi1 = mid1;
    }
    out[(size_t)n0 * OUTD + c] = __expf(-q0) * sLo[PAD(lo0)]
                               + __expf(q0)  * sHi[PAD(lo0)];
    out[(size_t)n1 * OUTD + c] = __expf(-q1) * sLo[PAD(lo1)]
                               + __expf(q1)  * sHi[PAD(lo1)];
}

extern "C" void kernel_launch(void* const* d_in, const int* in_sizes, int n_in,
                              void* d_out, int out_size, void* d_ws, size_t ws_size,
                              hipStream_t stream)
{
    const float* xc = (const float*)d_in[0];
    const float* yc = (const float*)d_in[1];
    const float* xt = (const float*)d_in[2];
    const float* W1 = (const float*)d_in[3];
    const float* b1 = (const float*)d_in[4];
    const float* W2 = (const float*)d_in[5];
    const float* b2 = (const float*)d_in[6];
    const float* W3 = (const float*)d_in[7];
    const float* b3 = (const float*)d_in[8];
    float* out = (float*)d_out;

    // workspace: vT [64][MM] (2MB) | skey [MM] | perm [MM]
    char* ws = (char*)d_ws;
    float* vT   = (float*)ws;
    float* skey = (float*)(ws + (size_t)OUTD * MM * 4);
    int*   perm = (int*)  (ws + (size_t)OUTD * MM * 4 + (size_t)MM * 4);

    rank_mlp_kernel<<<256, 1024, 0, stream>>>(xc, yc, W1, b1, W2, b2, W3, b3,
                                              vT, skey, perm);
    scan_query_kernel<<<256, 1024, 0, stream>>>(xt, skey, perm, vT, out);
}